// Round 2
// baseline (649.050 us; speedup 1.0000x reference)
//
#include <hip/hip_runtime.h>
#include <math.h>

#define NN   131072
#define CN   128
#define BN   64
#define NPGN 2048
#define MN   64
#define EN   1048576

typedef unsigned short u16;
typedef unsigned int   u32;

__device__ __forceinline__ float bf2f(u16 u){ return __uint_as_float(((u32)u)<<16); }
__device__ __forceinline__ u16 f2bf(float f){
  u32 x = __float_as_uint(f);
  return (u16)((x + 0x7fffu + ((x>>16)&1u)) >> 16);
}
__device__ __forceinline__ void unpack8u(uint4 w, u16* d){
  d[0]=(u16)(w.x&0xffffu); d[1]=(u16)(w.x>>16);
  d[2]=(u16)(w.y&0xffffu); d[3]=(u16)(w.y>>16);
  d[4]=(u16)(w.z&0xffffu); d[5]=(u16)(w.z>>16);
  d[6]=(u16)(w.w&0xffffu); d[7]=(u16)(w.w>>16);
}

// ---------------- graph build ----------------
__global__ void k_count(const int* __restrict__ dst, int* __restrict__ deg){
  int e = blockIdx.x*256 + threadIdx.x;
  atomicAdd(&deg[dst[e]], 1);
}

__global__ void k_scan1(const int* __restrict__ deg, int* __restrict__ rowst, int* __restrict__ bsum){
  __shared__ int s[512];
  const int t = threadIdx.x;
  const int i = blockIdx.x*512 + t;
  int v = deg[i];
  s[t] = v;
  __syncthreads();
  for (int off=1; off<512; off<<=1){
    int a = (t>=off) ? s[t-off] : 0;
    __syncthreads();
    s[t] += a;
    __syncthreads();
  }
  rowst[i] = s[t] - v;               // exclusive within block
  if (t==511) bsum[blockIdx.x] = s[511];
}

__global__ void k_scan2(const int* __restrict__ bsum, int* __restrict__ bofs){
  __shared__ int s[256];
  const int t = threadIdx.x;
  int v = bsum[t];
  s[t] = v;
  __syncthreads();
  for (int off=1; off<256; off<<=1){
    int a = (t>=off) ? s[t-off] : 0;
    __syncthreads();
    s[t] += a;
    __syncthreads();
  }
  bofs[t] = s[t] - v;                // exclusive over blocks
}

__global__ void k_scan3(int* __restrict__ rowst, const int* __restrict__ bofs){
  int i = blockIdx.x*256 + threadIdx.x;
  rowst[i] += bofs[i>>9];
}

__global__ void k_fill(const int* __restrict__ src, const int* __restrict__ dst,
                       const int* __restrict__ rowst, int* __restrict__ cursor,
                       int* __restrict__ csr){
  int e = blockIdx.x*256 + threadIdx.x;
  int d = dst[e];
  int p = atomicAdd(&cursor[d], 1);
  csr[rowst[d] + p] = src[e];
}

// ---------------- spectral path (fp32 I/O, fp32 accumulate) ----------------
// h_hat[b,m,c] = sum_n U[b,n,m] * h[b*NPG+n, c]; grid BN*4, K-chunks of 512 n.
__global__ void k_hhat(const float* __restrict__ U, const float* __restrict__ h, float* __restrict__ hp){
  __shared__ float su[16*MN];    // 4 KB
  __shared__ float sh[16*CN];    // 8 KB
  const int t = threadIdx.x;
  const int b = blockIdx.x >> 2;
  const int q = blockIdx.x & 3;
  const int mb = (t>>5)*8;
  const int cb = (t&31)*4;
  float acc[8][4] = {};
  const float* Ub = U + (size_t)b*NPGN*MN;
  const float* hb = h + (size_t)b*NPGN*CN;
  for (int n0 = q*512; n0 < q*512+512; n0 += 16){
    {
      const int idx = t*4;                               // 1024 U floats
      *(float4*)&su[idx] = *(const float4*)(Ub + (size_t)n0*MN + idx);
      const int jdx = t*8;                               // 2048 h floats
      *(float4*)&sh[jdx]   = *(const float4*)(hb + (size_t)n0*CN + jdx);
      *(float4*)&sh[jdx+4] = *(const float4*)(hb + (size_t)n0*CN + jdx + 4);
    }
    __syncthreads();
    #pragma unroll
    for (int nn=0; nn<16; ++nn){
      float4 hc = *(const float4*)&sh[nn*CN + cb];
      float4 u0 = *(const float4*)&su[nn*MN + mb];
      float4 u1 = *(const float4*)&su[nn*MN + mb + 4];
      float hv[4] = {hc.x,hc.y,hc.z,hc.w};
      float uv[8] = {u0.x,u0.y,u0.z,u0.w,u1.x,u1.y,u1.z,u1.w};
      #pragma unroll
      for (int i=0;i<8;++i)
        #pragma unroll
        for (int j=0;j<4;++j)
          acc[i][j] = fmaf(uv[i], hv[j], acc[i][j]);
    }
    __syncthreads();
  }
  float* dst0 = hp + (size_t)q*(BN*MN*CN);
  #pragma unroll
  for (int i=0;i<8;++i){
    float4 v0; v0.x=acc[i][0]; v0.y=acc[i][1]; v0.z=acc[i][2]; v0.w=acc[i][3];
    *(float4*)(dst0 + ((size_t)(b*MN + mb + i)*CN + cb)) = v0;
  }
}

// out_hat[b,m,o] = sum_c h_hat[b,m,c] * W[m,c,o]; grid 256 (m x 4 b-groups), 128 thr.
// W tile cast to bf16 in LDS (32 KB) to stay under the 64 KB static-LDS envelope.
__global__ void k_ohat(const float* __restrict__ W, const float* __restrict__ hp, float* __restrict__ ohat){
  __shared__ u16  sw[CN*CN];    // 32 KB
  __shared__ float shh[CN];
  const int t = threadIdx.x;
  const int m  = blockIdx.x & 63;
  const int bg = blockIdx.x >> 6;
  const float* Wm = W + (size_t)m*CN*CN;
  for (int j=0;j<32;++j){
    int idx = (j*128 + t)*4;
    float4 wv = *(const float4*)(Wm + idx);
    sw[idx+0]=f2bf(wv.x); sw[idx+1]=f2bf(wv.y); sw[idx+2]=f2bf(wv.z); sw[idx+3]=f2bf(wv.w);
  }
  __syncthreads();
  const int S = BN*MN*CN;
  for (int bb=0; bb<16; ++bb){
    int b = bg*16 + bb;
    int base = (b*MN + m)*CN + t;
    shh[t] = hp[base] + hp[S+base] + hp[2*S+base] + hp[3*S+base];
    __syncthreads();
    float acc = 0.f;
    for (int c=0;c<CN;++c) acc = fmaf(shh[c], bf2f(sw[c*CN+t]), acc);
    ohat[(size_t)(b*MN+m)*CN + t] = acc;
    __syncthreads();
  }
}

// spec[b,n,o] = sum_m U[b,n,m] * out_hat[b,m,o]; grid BN*16 (n-tiles of 128), 256 thr
__global__ void k_spec(const float* __restrict__ U, const float* __restrict__ ohat, float* __restrict__ spec){
  __shared__ float sU[128*MN];   // 32 KB
  __shared__ float sO[MN*CN];    // 32 KB
  const int t = threadIdx.x;
  const int b  = blockIdx.x >> 4;
  const int n0 = (blockIdx.x & 15)*128;
  const float* Ub = U + ((size_t)b*NPGN + n0)*MN;
  for (int j=0;j<8;++j){
    int idx = (j*256+t)*4;
    *(float4*)&sU[idx] = *(const float4*)(Ub + idx);
  }
  const float* Ob = ohat + (size_t)b*MN*CN;
  for (int j=0;j<8;++j){
    int idx = (j*256+t)*4;
    *(float4*)&sO[idx] = *(const float4*)(Ob + idx);
  }
  __syncthreads();
  const int i0 = (t>>5)*16;
  const int ob = (t&31)*4;
  float acc[16][4] = {};
  for (int m=0;m<MN;++m){
    float4 ov = *(const float4*)&sO[m*CN + ob];
    #pragma unroll
    for (int i=0;i<16;++i){
      float uv = sU[(i0+i)*MN + m];
      acc[i][0]=fmaf(uv,ov.x,acc[i][0]);
      acc[i][1]=fmaf(uv,ov.y,acc[i][1]);
      acc[i][2]=fmaf(uv,ov.z,acc[i][2]);
      acc[i][3]=fmaf(uv,ov.w,acc[i][3]);
    }
  }
  #pragma unroll
  for (int i=0;i<16;++i){
    float4 st; st.x=acc[i][0]; st.y=acc[i][1]; st.z=acc[i][2]; st.w=acc[i][3];
    *(float4*)(spec + ((size_t)b*NPGN + n0 + i0 + i)*CN + ob) = st;
  }
}

// ---------------- graph aggregate (neighbor mean) ----------------
__global__ void k_agg(const float* __restrict__ h, const int* __restrict__ rowst,
                      const int* __restrict__ deg, const int* __restrict__ csr,
                      u16* __restrict__ vnorm){
  const int t = threadIdx.x;
  const int node = blockIdx.x*2 + (t>>7);
  const int c = t & 127;
  const int rs = rowst[node];
  const int dg = deg[node];
  float a0=0.f,a1=0.f,a2=0.f,a3=0.f;
  int e = rs, re = rs + dg;
  for (; e+4<=re; e+=4){
    int s0=csr[e], s1=csr[e+1], s2=csr[e+2], s3=csr[e+3];
    a0 += h[(size_t)s0*CN + c];
    a1 += h[(size_t)s1*CN + c];
    a2 += h[(size_t)s2*CN + c];
    a3 += h[(size_t)s3*CN + c];
  }
  for (; e<re; ++e) a0 += h[(size_t)csr[e]*CN + c];
  float v = ((a0+a1)+(a2+a3)) / fmaxf((float)dg, 1.0f);
  vnorm[(size_t)node*CN + c] = f2bf(v);
}

// ---------------- local matvec + epilogue (LN + GELU) ----------------
// out currently holds spec (fp32); each row read before overwritten by same thread.
__global__ void k_localep(const float* __restrict__ h, const u16* __restrict__ vnorm,
                          const float* __restrict__ lin_w, const float* __restrict__ lin_b,
                          const float* __restrict__ ln_g, const float* __restrict__ ln_beta,
                          float* __restrict__ out){
  __shared__ u16   slw[CN*132];   // slw[c*132+o] = bf16(lin_w[o*128+c])  ~33.8 KB
  __shared__ u16   sv16[CN*33];   // sv16[c*33+i] = vnorm[(n0+i)*128+c]   ~8.4 KB
  __shared__ float sx[32*132];    // local result per node                ~16.9 KB
  const int t = threadIdx.x;
  const size_t n0 = (size_t)blockIdx.x*32;

  for (int j=0;j<16;++j){
    int idx = (j*256+t)*4;        // lin_w flat idx, 16384 floats total
    int o = idx>>7, c = idx&127;  // c in {0,4,...,124}: no carry into o
    float4 wv = *(const float4*)(lin_w + idx);
    slw[(c+0)*132 + o] = f2bf(wv.x);
    slw[(c+1)*132 + o] = f2bf(wv.y);
    slw[(c+2)*132 + o] = f2bf(wv.z);
    slw[(c+3)*132 + o] = f2bf(wv.w);
  }
  const u16* vb = vnorm + n0*CN;
  for (int j=0;j<2;++j){
    int idx = (j*256+t)*8;
    int nd = idx>>7, c = idx&127;
    uint4 vv = *(const uint4*)(vb + idx);
    u16 vl[8]; unpack8u(vv, vl);
    #pragma unroll
    for (int i=0;i<8;++i) sv16[(c+i)*33 + nd] = vl[i];
  }
  __syncthreads();

  const int ob = (t&31)*4;
  const int i0 = (t>>5)*4;
  float acc[4][4] = {};
  for (int c=0;c<CN;++c){
    ushort4 wq = *(const ushort4*)&slw[c*132 + ob];
    float w0=bf2f(wq.x), w1=bf2f(wq.y), w2=bf2f(wq.z), w3=bf2f(wq.w);
    const u16* vp = &sv16[c*33 + i0];
    float v0=bf2f(vp[0]), v1=bf2f(vp[1]), v2=bf2f(vp[2]), v3=bf2f(vp[3]);
    acc[0][0]=fmaf(v0,w0,acc[0][0]); acc[0][1]=fmaf(v0,w1,acc[0][1]);
    acc[0][2]=fmaf(v0,w2,acc[0][2]); acc[0][3]=fmaf(v0,w3,acc[0][3]);
    acc[1][0]=fmaf(v1,w0,acc[1][0]); acc[1][1]=fmaf(v1,w1,acc[1][1]);
    acc[1][2]=fmaf(v1,w2,acc[1][2]); acc[1][3]=fmaf(v1,w3,acc[1][3]);
    acc[2][0]=fmaf(v2,w0,acc[2][0]); acc[2][1]=fmaf(v2,w1,acc[2][1]);
    acc[2][2]=fmaf(v2,w2,acc[2][2]); acc[2][3]=fmaf(v2,w3,acc[2][3]);
    acc[3][0]=fmaf(v3,w0,acc[3][0]); acc[3][1]=fmaf(v3,w1,acc[3][1]);
    acc[3][2]=fmaf(v3,w2,acc[3][2]); acc[3][3]=fmaf(v3,w3,acc[3][3]);
  }
  #pragma unroll
  for (int i=0;i<4;++i){
    float4 st; st.x=acc[i][0]; st.y=acc[i][1]; st.z=acc[i][2]; st.w=acc[i][3];
    *(float4*)&sx[(i0+i)*132 + ob] = st;
  }
  __syncthreads();

  const int w = t>>6, lane = t&63;
  for (int r=0;r<8;++r){
    int i = r*4 + w;
    size_t base = (n0 + i)*CN;
    int c0 = lane, c1 = lane + 64;
    float x0 = h[base+c0] + out[base+c0] + sx[i*132+c0] + lin_b[c0];
    float x1 = h[base+c1] + out[base+c1] + sx[i*132+c1] + lin_b[c1];
    float s  = x0 + x1;
    float ss = fmaf(x0,x0, x1*x1);
    #pragma unroll
    for (int d=1; d<64; d<<=1){ s += __shfl_xor(s,d); ss += __shfl_xor(ss,d); }
    float mu  = s*(1.0f/128.0f);
    float var = ss*(1.0f/128.0f) - mu*mu;
    float rstd = rsqrtf(var + 1e-5f);
    float xn0 = (x0-mu)*rstd*ln_g[c0] + ln_beta[c0];
    float xn1 = (x1-mu)*rstd*ln_g[c1] + ln_beta[c1];
    float y0 = 0.5f*xn0*(1.0f + erff(xn0*0.70710678118654752f));
    float y1 = 0.5f*xn1*(1.0f + erff(xn1*0.70710678118654752f));
    out[base+c0] = y0;
    out[base+c1] = y1;
  }
}

extern "C" void kernel_launch(void* const* d_in, const int* in_sizes, int n_in,
                              void* d_out, int out_size, void* d_ws, size_t ws_size,
                              hipStream_t stream) {
  const float* h      = (const float*)d_in[0];
  const float* U      = (const float*)d_in[1];
  const float* W      = (const float*)d_in[2];
  const float* lin_w  = (const float*)d_in[3];
  const float* lin_b  = (const float*)d_in[4];
  const float* ln_g   = (const float*)d_in[5];
  const float* ln_b2  = (const float*)d_in[6];
  const int* ei       = (const int*)d_in[7];
  const int* src = ei;
  const int* dst = ei + EN;
  float* out = (float*)d_out;

  char* wp = (char*)d_ws;
  float* hp    = (float*)wp; wp += (size_t)4*BN*MN*CN*sizeof(float);   // 8 MB (4 K-partials)
  float* ohat  = (float*)wp; wp += (size_t)BN*MN*CN*sizeof(float);     // 2 MB
  u16*   vnorm = (u16*)wp;   wp += (size_t)NN*CN*sizeof(u16);          // 33.5 MB
  int*   deg   = (int*)wp;   wp += (size_t)NN*sizeof(int);
  int*   rowst = (int*)wp;   wp += (size_t)NN*sizeof(int);
  int*   cursor= (int*)wp;   wp += (size_t)NN*sizeof(int);
  int*   csr   = (int*)wp;   wp += (size_t)EN*sizeof(int);             // 4 MB
  int*   bsum  = (int*)wp;   wp += 512*sizeof(int);
  int*   bofs  = (int*)wp;   wp += 512*sizeof(int);

  hipMemsetAsync(deg,    0, (size_t)NN*sizeof(int), stream);
  hipMemsetAsync(cursor, 0, (size_t)NN*sizeof(int), stream);

  k_count<<<EN/256, 256, 0, stream>>>(dst, deg);
  k_scan1<<<NN/512, 512, 0, stream>>>(deg, rowst, bsum);
  k_scan2<<<1, 256, 0, stream>>>(bsum, bofs);
  k_scan3<<<NN/256, 256, 0, stream>>>(rowst, bofs);
  k_fill<<<EN/256, 256, 0, stream>>>(src, dst, rowst, cursor, csr);

  k_hhat<<<BN*4, 256, 0, stream>>>(U, h, hp);
  k_ohat<<<256, 128, 0, stream>>>(W, hp, ohat);
  k_spec<<<BN*16, 256, 0, stream>>>(U, ohat, out);   // spec parked in d_out (fp32)

  k_agg<<<NN/2, 256, 0, stream>>>(h, rowst, deg, csr, vnorm);
  k_localep<<<NN/32, 256, 0, stream>>>(h, vnorm, lin_w, lin_b, ln_g, ln_b2, out);
}

// Round 3
// 576.557 us; speedup vs baseline: 1.1257x; 1.1257x over previous
//
#include <hip/hip_runtime.h>
#include <math.h>

#define NN   131072
#define CN   128
#define BN   64
#define NPGN 2048
#define MN   64
#define EN   1048576

typedef unsigned short u16;
typedef unsigned int   u32;

__device__ __forceinline__ float bf2f(u16 u){ return __uint_as_float(((u32)u)<<16); }
__device__ __forceinline__ u16 f2bf(float f){
  u32 x = __float_as_uint(f);
  return (u16)((x + 0x7fffu + ((x>>16)&1u)) >> 16);
}

// ---------------- graph build ----------------
__global__ void k_count(const int* __restrict__ dst, int* __restrict__ deg){
  int e = blockIdx.x*256 + threadIdx.x;
  atomicAdd(&deg[dst[e]], 1);
}

__global__ void k_scan1(const int* __restrict__ deg, int* __restrict__ rowst, int* __restrict__ bsum){
  __shared__ int s[512];
  const int t = threadIdx.x;
  const int i = blockIdx.x*512 + t;
  int v = deg[i];
  s[t] = v;
  __syncthreads();
  for (int off=1; off<512; off<<=1){
    int a = (t>=off) ? s[t-off] : 0;
    __syncthreads();
    s[t] += a;
    __syncthreads();
  }
  rowst[i] = s[t] - v;               // exclusive within block
  if (t==511) bsum[blockIdx.x] = s[511];
}

__global__ void k_scan2(const int* __restrict__ bsum, int* __restrict__ bofs){
  __shared__ int s[256];
  const int t = threadIdx.x;
  int v = bsum[t];
  s[t] = v;
  __syncthreads();
  for (int off=1; off<256; off<<=1){
    int a = (t>=off) ? s[t-off] : 0;
    __syncthreads();
    s[t] += a;
    __syncthreads();
  }
  bofs[t] = s[t] - v;                // exclusive over blocks
}

__global__ void k_scan3(int* __restrict__ rowst, const int* __restrict__ bofs){
  int i = blockIdx.x*256 + threadIdx.x;
  rowst[i] += bofs[i>>9];
}

__global__ void k_fill(const int* __restrict__ src, const int* __restrict__ dst,
                       const int* __restrict__ rowst, int* __restrict__ cursor,
                       int* __restrict__ csr){
  int e = blockIdx.x*256 + threadIdx.x;
  int d = dst[e];
  int p = atomicAdd(&cursor[d], 1);
  csr[rowst[d] + p] = src[e];
}

// ---------------- weight pre-transpose (once per launch) ----------------
// wT[c*128+o] = bf16(lin_w[o*128+c])
__global__ void k_prepw(const float* __restrict__ lin_w, u16* __restrict__ wT){
  int idx = blockIdx.x*256 + threadIdx.x;   // 16384 total
  int o = idx>>7, c = idx&127;
  wT[c*CN + o] = f2bf(lin_w[idx]);
}

// ---------------- spectral path (fp32 I/O, fp32 accumulate) ----------------
// h_hat[b,m,c] = sum_n U[b,n,m] * h[b*NPG+n, c]; grid BN*4, K-chunks of 512 n.
__global__ void k_hhat(const float* __restrict__ U, const float* __restrict__ h, float* __restrict__ hp){
  __shared__ float su[16*MN];    // 4 KB
  __shared__ float sh[16*CN];    // 8 KB
  const int t = threadIdx.x;
  const int b = blockIdx.x >> 2;
  const int q = blockIdx.x & 3;
  const int mb = (t>>5)*8;
  const int cb = (t&31)*4;
  float acc[8][4] = {};
  const float* Ub = U + (size_t)b*NPGN*MN;
  const float* hb = h + (size_t)b*NPGN*CN;
  for (int n0 = q*512; n0 < q*512+512; n0 += 16){
    {
      const int idx = t*4;                               // 1024 U floats
      *(float4*)&su[idx] = *(const float4*)(Ub + (size_t)n0*MN + idx);
      const int jdx = t*8;                               // 2048 h floats
      *(float4*)&sh[jdx]   = *(const float4*)(hb + (size_t)n0*CN + jdx);
      *(float4*)&sh[jdx+4] = *(const float4*)(hb + (size_t)n0*CN + jdx + 4);
    }
    __syncthreads();
    #pragma unroll
    for (int nn=0; nn<16; ++nn){
      float4 hc = *(const float4*)&sh[nn*CN + cb];
      float4 u0 = *(const float4*)&su[nn*MN + mb];
      float4 u1 = *(const float4*)&su[nn*MN + mb + 4];
      float hv[4] = {hc.x,hc.y,hc.z,hc.w};
      float uv[8] = {u0.x,u0.y,u0.z,u0.w,u1.x,u1.y,u1.z,u1.w};
      #pragma unroll
      for (int i=0;i<8;++i)
        #pragma unroll
        for (int j=0;j<4;++j)
          acc[i][j] = fmaf(uv[i], hv[j], acc[i][j]);
    }
    __syncthreads();
  }
  float* dst0 = hp + (size_t)q*(BN*MN*CN);
  #pragma unroll
  for (int i=0;i<8;++i){
    float4 v0; v0.x=acc[i][0]; v0.y=acc[i][1]; v0.z=acc[i][2]; v0.w=acc[i][3];
    *(float4*)(dst0 + ((size_t)(b*MN + mb + i)*CN + cb)) = v0;
  }
}

// out_hat[b,m,o] = sum_c h_hat[b,m,c] * W[m,c,o]; grid 256 (m x 4 b-groups), 128 thr.
__global__ void k_ohat(const float* __restrict__ W, const float* __restrict__ hp, float* __restrict__ ohat){
  __shared__ u16  sw[CN*CN];    // 32 KB
  __shared__ float shh[CN];
  const int t = threadIdx.x;
  const int m  = blockIdx.x & 63;
  const int bg = blockIdx.x >> 6;
  const float* Wm = W + (size_t)m*CN*CN;
  for (int j=0;j<32;++j){
    int idx = (j*128 + t)*4;
    float4 wv = *(const float4*)(Wm + idx);
    sw[idx+0]=f2bf(wv.x); sw[idx+1]=f2bf(wv.y); sw[idx+2]=f2bf(wv.z); sw[idx+3]=f2bf(wv.w);
  }
  __syncthreads();
  const int S = BN*MN*CN;
  for (int bb=0; bb<16; ++bb){
    int b = bg*16 + bb;
    int base = (b*MN + m)*CN + t;
    shh[t] = hp[base] + hp[S+base] + hp[2*S+base] + hp[3*S+base];
    __syncthreads();
    float acc = 0.f;
    for (int c=0;c<CN;++c) acc = fmaf(shh[c], bf2f(sw[c*CN+t]), acc);
    ohat[(size_t)(b*MN+m)*CN + t] = acc;
    __syncthreads();
  }
}

// spec[b,n,o] = sum_m U[b,n,m] * out_hat[b,m,o]; grid BN*16 (n-tiles of 128), 256 thr
__global__ void k_spec(const float* __restrict__ U, const float* __restrict__ ohat, float* __restrict__ spec){
  __shared__ float sU[128*MN];   // 32 KB
  __shared__ float sO[MN*CN];    // 32 KB
  const int t = threadIdx.x;
  const int b  = blockIdx.x >> 4;
  const int n0 = (blockIdx.x & 15)*128;
  const float* Ub = U + ((size_t)b*NPGN + n0)*MN;
  for (int j=0;j<8;++j){
    int idx = (j*256+t)*4;
    *(float4*)&sU[idx] = *(const float4*)(Ub + idx);
  }
  const float* Ob = ohat + (size_t)b*MN*CN;
  for (int j=0;j<8;++j){
    int idx = (j*256+t)*4;
    *(float4*)&sO[idx] = *(const float4*)(Ob + idx);
  }
  __syncthreads();
  const int i0 = (t>>5)*16;
  const int ob = (t&31)*4;
  float acc[16][4] = {};
  for (int m=0;m<MN;++m){
    float4 ov = *(const float4*)&sO[m*CN + ob];
    #pragma unroll
    for (int i=0;i<16;++i){
      float uv = sU[(i0+i)*MN + m];
      acc[i][0]=fmaf(uv,ov.x,acc[i][0]);
      acc[i][1]=fmaf(uv,ov.y,acc[i][1]);
      acc[i][2]=fmaf(uv,ov.z,acc[i][2]);
      acc[i][3]=fmaf(uv,ov.w,acc[i][3]);
    }
  }
  #pragma unroll
  for (int i=0;i<16;++i){
    float4 st; st.x=acc[i][0]; st.y=acc[i][1]; st.z=acc[i][2]; st.w=acc[i][3];
    *(float4*)(spec + ((size_t)b*NPGN + n0 + i0 + i)*CN + ob) = st;
  }
}

// ---------------- graph aggregate (neighbor mean) ----------------
__global__ void k_agg(const float* __restrict__ h, const int* __restrict__ rowst,
                      const int* __restrict__ deg, const int* __restrict__ csr,
                      u16* __restrict__ vnorm){
  const int t = threadIdx.x;
  const int node = blockIdx.x*2 + (t>>7);
  const int c = t & 127;
  const int rs = rowst[node];
  const int dg = deg[node];
  float a0=0.f,a1=0.f,a2=0.f,a3=0.f;
  int e = rs, re = rs + dg;
  for (; e+4<=re; e+=4){
    int s0=csr[e], s1=csr[e+1], s2=csr[e+2], s3=csr[e+3];
    a0 += h[(size_t)s0*CN + c];
    a1 += h[(size_t)s1*CN + c];
    a2 += h[(size_t)s2*CN + c];
    a3 += h[(size_t)s3*CN + c];
  }
  for (; e<re; ++e) a0 += h[(size_t)csr[e]*CN + c];
  float v = ((a0+a1)+(a2+a3)) / fmaxf((float)dg, 1.0f);
  vnorm[(size_t)node*CN + c] = f2bf(v);
}

// ---------------- local matvec + epilogue (LN + GELU) ----------------
// out currently holds spec (fp32); each row read before overwritten by same wave.
// wT is pre-transposed bf16 lin_w (wT[c*128+o]); all LDS staging is stride-1.
__global__ void k_localep(const float* __restrict__ h, const u16* __restrict__ vnorm,
                          const u16* __restrict__ wT, const float* __restrict__ lin_b,
                          const float* __restrict__ ln_g, const float* __restrict__ ln_beta,
                          float* __restrict__ out){
  __shared__ u16   swT[CN*CN];    // 32 KB   swT[c*128+o]
  __shared__ u16   sv[32*CN];     // 8 KB    sv[i*128+c]  (natural layout)
  __shared__ float sx[32*132];    // 16.9 KB local result per node (pad 132)
  const int t = threadIdx.x;
  const size_t n0 = (size_t)blockIdx.x*32;

  // stage weights: 16384 u16 = 2048 uint4, stride-1, conflict-free
  #pragma unroll
  for (int j=0;j<8;++j){
    int idx = (j*256+t)*8;
    *(uint4*)&swT[idx] = *(const uint4*)(wT + idx);
  }
  // stage vnorm rows: 4096 u16 = 512 uint4
  const u16* vb = vnorm + n0*CN;
  #pragma unroll
  for (int j=0;j<2;++j){
    int idx = (j*256+t)*8;
    *(uint4*)&sv[idx] = *(const uint4*)(vb + idx);
  }
  __syncthreads();

  const int ob = (t&31)*4;        // 4 outputs per thread
  const int i0 = (t>>5)*4;        // 4 nodes per thread
  float acc[4][4] = {};
  for (int c=0;c<CN;++c){
    ushort4 wq = *(const ushort4*)&swT[c*CN + ob];          // 2-way aliased: free
    float w0=bf2f(wq.x), w1=bf2f(wq.y), w2=bf2f(wq.z), w3=bf2f(wq.w);
    const u16* vp = &sv[i0*CN + c];                          // uniform per 32-group: broadcast
    float v0=bf2f(vp[0]), v1=bf2f(vp[CN]), v2=bf2f(vp[2*CN]), v3=bf2f(vp[3*CN]);
    acc[0][0]=fmaf(v0,w0,acc[0][0]); acc[0][1]=fmaf(v0,w1,acc[0][1]);
    acc[0][2]=fmaf(v0,w2,acc[0][2]); acc[0][3]=fmaf(v0,w3,acc[0][3]);
    acc[1][0]=fmaf(v1,w0,acc[1][0]); acc[1][1]=fmaf(v1,w1,acc[1][1]);
    acc[1][2]=fmaf(v1,w2,acc[1][2]); acc[1][3]=fmaf(v1,w3,acc[1][3]);
    acc[2][0]=fmaf(v2,w0,acc[2][0]); acc[2][1]=fmaf(v2,w1,acc[2][1]);
    acc[2][2]=fmaf(v2,w2,acc[2][2]); acc[2][3]=fmaf(v2,w3,acc[2][3]);
    acc[3][0]=fmaf(v3,w0,acc[3][0]); acc[3][1]=fmaf(v3,w1,acc[3][1]);
    acc[3][2]=fmaf(v3,w2,acc[3][2]); acc[3][3]=fmaf(v3,w3,acc[3][3]);
  }
  #pragma unroll
  for (int i=0;i<4;++i){
    float4 st; st.x=acc[i][0]; st.y=acc[i][1]; st.z=acc[i][2]; st.w=acc[i][3];
    *(float4*)&sx[(i0+i)*132 + ob] = st;
  }
  __syncthreads();

  const int w = t>>6, lane = t&63;
  for (int r=0;r<8;++r){
    int i = r*4 + w;
    size_t base = (n0 + i)*CN;
    int c0 = lane, c1 = lane + 64;
    float x0 = h[base+c0] + out[base+c0] + sx[i*132+c0] + lin_b[c0];
    float x1 = h[base+c1] + out[base+c1] + sx[i*132+c1] + lin_b[c1];
    float s  = x0 + x1;
    float ss = fmaf(x0,x0, x1*x1);
    #pragma unroll
    for (int d=1; d<64; d<<=1){ s += __shfl_xor(s,d); ss += __shfl_xor(ss,d); }
    float mu  = s*(1.0f/128.0f);
    float var = ss*(1.0f/128.0f) - mu*mu;
    float rstd = rsqrtf(var + 1e-5f);
    float xn0 = (x0-mu)*rstd*ln_g[c0] + ln_beta[c0];
    float xn1 = (x1-mu)*rstd*ln_g[c1] + ln_beta[c1];
    float y0 = 0.5f*xn0*(1.0f + erff(xn0*0.70710678118654752f));
    float y1 = 0.5f*xn1*(1.0f + erff(xn1*0.70710678118654752f));
    out[base+c0] = y0;
    out[base+c1] = y1;
  }
}

extern "C" void kernel_launch(void* const* d_in, const int* in_sizes, int n_in,
                              void* d_out, int out_size, void* d_ws, size_t ws_size,
                              hipStream_t stream) {
  const float* h      = (const float*)d_in[0];
  const float* U      = (const float*)d_in[1];
  const float* W      = (const float*)d_in[2];
  const float* lin_w  = (const float*)d_in[3];
  const float* lin_b  = (const float*)d_in[4];
  const float* ln_g   = (const float*)d_in[5];
  const float* ln_b2  = (const float*)d_in[6];
  const int* ei       = (const int*)d_in[7];
  const int* src = ei;
  const int* dst = ei + EN;
  float* out = (float*)d_out;

  char* wp = (char*)d_ws;
  float* hp    = (float*)wp; wp += (size_t)4*BN*MN*CN*sizeof(float);   // 8 MB (4 K-partials)
  float* ohat  = (float*)wp; wp += (size_t)BN*MN*CN*sizeof(float);     // 2 MB
  u16*   vnorm = (u16*)wp;   wp += (size_t)NN*CN*sizeof(u16);          // 33.5 MB
  u16*   wT    = (u16*)wp;   wp += (size_t)CN*CN*sizeof(u16);          // 32 KB
  int*   deg   = (int*)wp;   wp += (size_t)NN*sizeof(int);
  int*   rowst = (int*)wp;   wp += (size_t)NN*sizeof(int);
  int*   cursor= (int*)wp;   wp += (size_t)NN*sizeof(int);
  int*   csr   = (int*)wp;   wp += (size_t)EN*sizeof(int);             // 4 MB
  int*   bsum  = (int*)wp;   wp += 512*sizeof(int);
  int*   bofs  = (int*)wp;   wp += 512*sizeof(int);

  hipMemsetAsync(deg,    0, (size_t)NN*sizeof(int), stream);
  hipMemsetAsync(cursor, 0, (size_t)NN*sizeof(int), stream);

  k_count<<<EN/256, 256, 0, stream>>>(dst, deg);
  k_scan1<<<NN/512, 512, 0, stream>>>(deg, rowst, bsum);
  k_scan2<<<1, 256, 0, stream>>>(bsum, bofs);
  k_scan3<<<NN/256, 256, 0, stream>>>(rowst, bofs);
  k_fill<<<EN/256, 256, 0, stream>>>(src, dst, rowst, cursor, csr);

  k_prepw<<<64, 256, 0, stream>>>(lin_w, wT);

  k_hhat<<<BN*4, 256, 0, stream>>>(U, h, hp);
  k_ohat<<<256, 128, 0, stream>>>(W, hp, ohat);
  k_spec<<<BN*16, 256, 0, stream>>>(U, ohat, out);   // spec parked in d_out (fp32)

  k_agg<<<NN/2, 256, 0, stream>>>(h, rowst, deg, csr, vnorm);
  k_localep<<<NN/32, 256, 0, stream>>>(h, vnorm, wT, lin_b, ln_g, ln_b2, out);
}

// Round 4
// 477.511 us; speedup vs baseline: 1.3592x; 1.2074x over previous
//
#include <hip/hip_runtime.h>
#include <math.h>

#define NN   131072
#define CN   128
#define BN   64
#define NPGN 2048
#define MN   64
#define EN   1048576

typedef unsigned short u16;
typedef unsigned int   u32;
typedef __attribute__((ext_vector_type(8))) short short8;
typedef __attribute__((ext_vector_type(4))) float f32x4;

__device__ __forceinline__ float bf2f(u16 u){ return __uint_as_float(((u32)u)<<16); }
__device__ __forceinline__ u16 f2bf(float f){
  u32 x = __float_as_uint(f);
  return (u16)((x + 0x7fffu + ((x>>16)&1u)) >> 16);
}

// ---------------- graph build ----------------
__global__ void k_count(const int* __restrict__ dst, int* __restrict__ deg){
  int e = blockIdx.x*256 + threadIdx.x;
  atomicAdd(&deg[dst[e]], 1);
}

__global__ void k_scan1(const int* __restrict__ deg, int* __restrict__ rowst, int* __restrict__ bsum){
  __shared__ int s[512];
  const int t = threadIdx.x;
  const int i = blockIdx.x*512 + t;
  int v = deg[i];
  s[t] = v;
  __syncthreads();
  for (int off=1; off<512; off<<=1){
    int a = (t>=off) ? s[t-off] : 0;
    __syncthreads();
    s[t] += a;
    __syncthreads();
  }
  rowst[i] = s[t] - v;               // exclusive within block
  if (t==511) bsum[blockIdx.x] = s[511];
}

__global__ void k_scan2(const int* __restrict__ bsum, int* __restrict__ bofs){
  __shared__ int s[256];
  const int t = threadIdx.x;
  int v = bsum[t];
  s[t] = v;
  __syncthreads();
  for (int off=1; off<256; off<<=1){
    int a = (t>=off) ? s[t-off] : 0;
    __syncthreads();
    s[t] += a;
    __syncthreads();
  }
  bofs[t] = s[t] - v;                // exclusive over blocks
}

__global__ void k_scan3(int* __restrict__ rowst, const int* __restrict__ bofs){
  int i = blockIdx.x*256 + threadIdx.x;
  rowst[i] += bofs[i>>9];
}

__global__ void k_fill(const int* __restrict__ src, const int* __restrict__ dst,
                       const int* __restrict__ rowst, int* __restrict__ cursor,
                       int* __restrict__ csr){
  int e = blockIdx.x*256 + threadIdx.x;
  int d = dst[e];
  int p = atomicAdd(&cursor[d], 1);
  csr[rowst[d] + p] = src[e];
}

// ---------------- weight prep: B-fragment-swizzled bf16 lin_w ----------------
// local[n][o] = sum_c vnorm[n][c] * lin_w[o][c]  =>  B[k=c][n=o] = lin_w[o*128+c]
// Fragment layout for mfma_f32_16x16x32_bf16 B-operand: lane L holds
// B[k = ks*32 + (L>>4)*8 + j][o = ct*16 + (L&15)], j=0..7 contiguous.
// wsw[((ct*4+ks)*64 + L)*8 + j]
__global__ void k_prepw(const float* __restrict__ lin_w, u16* __restrict__ wsw){
  int tid = blockIdx.x*256 + threadIdx.x;   // 2048 total
  int g = tid >> 6, L = tid & 63;
  int ct = g >> 2, ks = g & 3;
  int o = L & 15, q = L >> 4;
  const float* srcp = lin_w + (ct*16+o)*CN + ks*32 + q*8;
  u16 tmp[8];
  #pragma unroll
  for (int j=0;j<8;++j) tmp[j] = f2bf(srcp[j]);
  *(uint4*)(wsw + (size_t)tid*8) = *(const uint4*)tmp;
}

// ---------------- spectral path (fp32 I/O, fp32 accumulate) ----------------
// h_hat[b,m,c] = sum_n U[b,n,m] * h[b*NPG+n, c]; grid BN*8, K-chunks of 256 n.
__global__ void k_hhat(const float* __restrict__ U, const float* __restrict__ h, float* __restrict__ hp){
  __shared__ float su[16*MN];    // 4 KB
  __shared__ float sh[16*CN];    // 8 KB
  const int t = threadIdx.x;
  const int b = blockIdx.x >> 3;
  const int q = blockIdx.x & 7;
  const int mb = (t>>5)*8;
  const int cb = (t&31)*4;
  float acc[8][4] = {};
  const float* Ub = U + (size_t)b*NPGN*MN;
  const float* hb = h + (size_t)b*NPGN*CN;
  for (int n0 = q*256; n0 < q*256+256; n0 += 16){
    {
      const int idx = t*4;                               // 1024 U floats
      *(float4*)&su[idx] = *(const float4*)(Ub + (size_t)n0*MN + idx);
      const int jdx = t*8;                               // 2048 h floats
      *(float4*)&sh[jdx]   = *(const float4*)(hb + (size_t)n0*CN + jdx);
      *(float4*)&sh[jdx+4] = *(const float4*)(hb + (size_t)n0*CN + jdx + 4);
    }
    __syncthreads();
    #pragma unroll
    for (int nn=0; nn<16; ++nn){
      float4 hc = *(const float4*)&sh[nn*CN + cb];
      float4 u0 = *(const float4*)&su[nn*MN + mb];
      float4 u1 = *(const float4*)&su[nn*MN + mb + 4];
      float hv[4] = {hc.x,hc.y,hc.z,hc.w};
      float uv[8] = {u0.x,u0.y,u0.z,u0.w,u1.x,u1.y,u1.z,u1.w};
      #pragma unroll
      for (int i=0;i<8;++i)
        #pragma unroll
        for (int j=0;j<4;++j)
          acc[i][j] = fmaf(uv[i], hv[j], acc[i][j]);
    }
    __syncthreads();
  }
  float* dst0 = hp + (size_t)q*(BN*MN*CN);
  #pragma unroll
  for (int i=0;i<8;++i){
    float4 v0; v0.x=acc[i][0]; v0.y=acc[i][1]; v0.z=acc[i][2]; v0.w=acc[i][3];
    *(float4*)(dst0 + ((size_t)(b*MN + mb + i)*CN + cb)) = v0;
  }
}

// out_hat[b,m,o] = sum_c h_hat[b,m,c] * W[m,c,o]; grid 256 (m x 4 b-groups), 128 thr.
__global__ void k_ohat(const float* __restrict__ W, const float* __restrict__ hp, float* __restrict__ ohat){
  __shared__ u16  sw[CN*CN];    // 32 KB
  __shared__ float shh[CN];
  const int t = threadIdx.x;
  const int m  = blockIdx.x & 63;
  const int bg = blockIdx.x >> 6;
  const float* Wm = W + (size_t)m*CN*CN;
  for (int j=0;j<32;++j){
    int idx = (j*128 + t)*4;
    float4 wv = *(const float4*)(Wm + idx);
    sw[idx+0]=f2bf(wv.x); sw[idx+1]=f2bf(wv.y); sw[idx+2]=f2bf(wv.z); sw[idx+3]=f2bf(wv.w);
  }
  __syncthreads();
  const int S = BN*MN*CN;
  for (int bb=0; bb<16; ++bb){
    int b = bg*16 + bb;
    int base = (b*MN + m)*CN + t;
    float a = 0.f;
    #pragma unroll
    for (int p=0;p<8;++p) a += hp[(size_t)p*S + base];
    shh[t] = a;
    __syncthreads();
    float acc = 0.f;
    for (int c=0;c<CN;++c) acc = fmaf(shh[c], bf2f(sw[c*CN+t]), acc);
    ohat[(size_t)(b*MN+m)*CN + t] = acc;
    __syncthreads();
  }
}

// spec[b,n,o] = sum_m U[b,n,m] * out_hat[b,m,o]; grid BN*16 (n-tiles of 128), 256 thr
__global__ void k_spec(const float* __restrict__ U, const float* __restrict__ ohat, float* __restrict__ spec){
  __shared__ float sU[128*MN];   // 32 KB
  __shared__ float sO[MN*CN];    // 32 KB
  const int t = threadIdx.x;
  const int b  = blockIdx.x >> 4;
  const int n0 = (blockIdx.x & 15)*128;
  const float* Ub = U + ((size_t)b*NPGN + n0)*MN;
  for (int j=0;j<8;++j){
    int idx = (j*256+t)*4;
    *(float4*)&sU[idx] = *(const float4*)(Ub + idx);
  }
  const float* Ob = ohat + (size_t)b*MN*CN;
  for (int j=0;j<8;++j){
    int idx = (j*256+t)*4;
    *(float4*)&sO[idx] = *(const float4*)(Ob + idx);
  }
  __syncthreads();
  const int i0 = (t>>5)*16;
  const int ob = (t&31)*4;
  float acc[16][4] = {};
  for (int m=0;m<MN;++m){
    float4 ov = *(const float4*)&sO[m*CN + ob];
    #pragma unroll
    for (int i=0;i<16;++i){
      float uv = sU[(i0+i)*MN + m];
      acc[i][0]=fmaf(uv,ov.x,acc[i][0]);
      acc[i][1]=fmaf(uv,ov.y,acc[i][1]);
      acc[i][2]=fmaf(uv,ov.z,acc[i][2]);
      acc[i][3]=fmaf(uv,ov.w,acc[i][3]);
    }
  }
  #pragma unroll
  for (int i=0;i<16;++i){
    float4 st; st.x=acc[i][0]; st.y=acc[i][1]; st.z=acc[i][2]; st.w=acc[i][3];
    *(float4*)(spec + ((size_t)b*NPGN + n0 + i0 + i)*CN + ob) = st;
  }
}

// ---------------- graph aggregate (neighbor mean) ----------------
__global__ void k_agg(const float* __restrict__ h, const int* __restrict__ rowst,
                      const int* __restrict__ deg, const int* __restrict__ csr,
                      u16* __restrict__ vnorm){
  const int t = threadIdx.x;
  const int node = blockIdx.x*2 + (t>>7);
  const int c = t & 127;
  const int rs = rowst[node];
  const int dg = deg[node];
  float a0=0.f,a1=0.f,a2=0.f,a3=0.f;
  int e = rs, re = rs + dg;
  for (; e+4<=re; e+=4){
    int s0=csr[e], s1=csr[e+1], s2=csr[e+2], s3=csr[e+3];
    a0 += h[(size_t)s0*CN + c];
    a1 += h[(size_t)s1*CN + c];
    a2 += h[(size_t)s2*CN + c];
    a3 += h[(size_t)s3*CN + c];
  }
  for (; e<re; ++e) a0 += h[(size_t)csr[e]*CN + c];
  float v = ((a0+a1)+(a2+a3)) / fmaxf((float)dg, 1.0f);
  vnorm[(size_t)node*CN + c] = f2bf(v);
}

// ---------------- local matvec (MFMA) + epilogue (LN + GELU) ----------------
// out currently holds spec (fp32); each row read before overwritten by same wave.
// local = sv(32x128 bf16) @ B(128x128 bf16) via 16x16x32 MFMA.
// Wave w: row-tile rt=w&1 (16 nodes), col-half cb=w>>1 (4 col-tiles of 16).
__global__ __launch_bounds__(256,4) void k_localep(
                          const float* __restrict__ h, const u16* __restrict__ vnorm,
                          const u16* __restrict__ wsw, const float* __restrict__ lin_b,
                          const float* __restrict__ ln_g, const float* __restrict__ ln_beta,
                          float* __restrict__ out){
  __shared__ u16   sv[32*136];    // 8.5 KB, rows padded to 136 u16 (16B-aligned rows)
  __shared__ float sx[32*132];    // 16.9 KB local result per node (pad 132)
  const int t = threadIdx.x;
  const int w = t>>6, lane = t&63;
  const size_t n0 = (size_t)blockIdx.x*32;

  // stage vnorm rows (natural layout, padded): 512 uint4
  const u16* vb = vnorm + n0*CN;
  #pragma unroll
  for (int j=0;j<2;++j){
    int idx = (j*256+t)*8;
    int row = idx>>7, col = idx&127;
    *(uint4*)&sv[row*136+col] = *(const uint4*)(vb + idx);
  }
  __syncthreads();

  const int rt = w&1, cb = w>>1;
  f32x4 acc[4] = {{0.f,0.f,0.f,0.f},{0.f,0.f,0.f,0.f},{0.f,0.f,0.f,0.f},{0.f,0.f,0.f,0.f}};
  #pragma unroll
  for (int ks=0; ks<4; ++ks){
    // A-frag: A[m=lane&15][k=ks*32+(lane>>4)*8+j]
    short8 af = *(const short8*)&sv[(rt*16 + (lane&15))*136 + ks*32 + (lane>>4)*8];
    #pragma unroll
    for (int c4=0; c4<4; ++c4){
      const short8 bf = *(const short8*)(wsw + ((size_t)((cb*4+c4)*4+ks)*64 + lane)*8);
      acc[c4] = __builtin_amdgcn_mfma_f32_16x16x32_bf16(af, bf, acc[c4], 0, 0, 0);
    }
  }
  // C layout: col=lane&15, row=(lane>>4)*4+reg  (m89-verified)
  #pragma unroll
  for (int c4=0; c4<4; ++c4){
    int col = cb*64 + c4*16 + (lane&15);
    int rbase = rt*16 + (lane>>4)*4;
    #pragma unroll
    for (int r=0; r<4; ++r) sx[(rbase+r)*132 + col] = acc[c4][r];
  }
  __syncthreads();

  const int lane2 = t&63, w2 = t>>6;
  for (int r=0;r<8;++r){
    int i = r*4 + w2;
    size_t base = (n0 + i)*CN;
    int c0 = lane2, c1 = lane2 + 64;
    float x0 = h[base+c0] + out[base+c0] + sx[i*132+c0] + lin_b[c0];
    float x1 = h[base+c1] + out[base+c1] + sx[i*132+c1] + lin_b[c1];
    float s  = x0 + x1;
    float ss = fmaf(x0,x0, x1*x1);
    #pragma unroll
    for (int d=1; d<64; d<<=1){ s += __shfl_xor(s,d); ss += __shfl_xor(ss,d); }
    float mu  = s*(1.0f/128.0f);
    float var = ss*(1.0f/128.0f) - mu*mu;
    float rstd = rsqrtf(var + 1e-5f);
    float xn0 = (x0-mu)*rstd*ln_g[c0] + ln_beta[c0];
    float xn1 = (x1-mu)*rstd*ln_g[c1] + ln_beta[c1];
    float y0 = 0.5f*xn0*(1.0f + erff(xn0*0.70710678118654752f));
    float y1 = 0.5f*xn1*(1.0f + erff(xn1*0.70710678118654752f));
    out[base+c0] = y0;
    out[base+c1] = y1;
  }
}

extern "C" void kernel_launch(void* const* d_in, const int* in_sizes, int n_in,
                              void* d_out, int out_size, void* d_ws, size_t ws_size,
                              hipStream_t stream) {
  const float* h      = (const float*)d_in[0];
  const float* U      = (const float*)d_in[1];
  const float* W      = (const float*)d_in[2];
  const float* lin_w  = (const float*)d_in[3];
  const float* lin_b  = (const float*)d_in[4];
  const float* ln_g   = (const float*)d_in[5];
  const float* ln_b2  = (const float*)d_in[6];
  const int* ei       = (const int*)d_in[7];
  const int* src = ei;
  const int* dst = ei + EN;
  float* out = (float*)d_out;

  char* wp = (char*)d_ws;
  float* hp    = (float*)wp; wp += (size_t)8*BN*MN*CN*sizeof(float);   // 16 MB (8 K-partials)
  float* ohat  = (float*)wp; wp += (size_t)BN*MN*CN*sizeof(float);     // 2 MB
  u16*   vnorm = (u16*)wp;   wp += (size_t)NN*CN*sizeof(u16);          // 33.5 MB
  u16*   wsw   = (u16*)wp;   wp += (size_t)CN*CN*sizeof(u16);          // 32 KB
  int*   deg   = (int*)wp;   wp += (size_t)NN*sizeof(int);
  int*   rowst = (int*)wp;   wp += (size_t)NN*sizeof(int);
  int*   cursor= (int*)wp;   wp += (size_t)NN*sizeof(int);
  int*   csr   = (int*)wp;   wp += (size_t)EN*sizeof(int);             // 4 MB
  int*   bsum  = (int*)wp;   wp += 512*sizeof(int);
  int*   bofs  = (int*)wp;   wp += 512*sizeof(int);

  hipMemsetAsync(deg,    0, (size_t)NN*sizeof(int), stream);
  hipMemsetAsync(cursor, 0, (size_t)NN*sizeof(int), stream);

  k_count<<<EN/256, 256, 0, stream>>>(dst, deg);
  k_scan1<<<NN/512, 512, 0, stream>>>(deg, rowst, bsum);
  k_scan2<<<1, 256, 0, stream>>>(bsum, bofs);
  k_scan3<<<NN/256, 256, 0, stream>>>(rowst, bofs);
  k_fill<<<EN/256, 256, 0, stream>>>(src, dst, rowst, cursor, csr);

  k_prepw<<<8, 256, 0, stream>>>(lin_w, wsw);

  k_hhat<<<BN*8, 256, 0, stream>>>(U, h, hp);
  k_ohat<<<256, 128, 0, stream>>>(W, hp, ohat);
  k_spec<<<BN*16, 256, 0, stream>>>(U, ohat, out);   // spec parked in d_out (fp32)

  k_agg<<<NN/2, 256, 0, stream>>>(h, rowst, deg, csr, vnorm);
  k_localep<<<NN/32, 256, 0, stream>>>(h, vnorm, wsw, lin_b, ln_g, ln_b2, out);
}

// Round 5
// 465.670 us; speedup vs baseline: 1.3938x; 1.0254x over previous
//
#include <hip/hip_runtime.h>
#include <math.h>

#define NN   131072
#define CN   128
#define BN   64
#define NPGN 2048
#define MN   64
#define EN   1048576

typedef unsigned short u16;
typedef unsigned int   u32;
typedef __attribute__((ext_vector_type(8))) short short8;
typedef __attribute__((ext_vector_type(4))) float f32x4;

__device__ __forceinline__ float bf2f(u16 u){ return __uint_as_float(((u32)u)<<16); }
__device__ __forceinline__ u16 f2bf(float f){
  u32 x = __float_as_uint(f);
  return (u16)((x + 0x7fffu + ((x>>16)&1u)) >> 16);
}

// ---------------- graph build ----------------
__global__ void k_count(const int* __restrict__ dst, int* __restrict__ deg){
  int e = blockIdx.x*256 + threadIdx.x;
  atomicAdd(&deg[dst[e]], 1);
}

__global__ void k_scan1(const int* __restrict__ deg, int* __restrict__ rowst, int* __restrict__ bsum){
  __shared__ int s[512];
  const int t = threadIdx.x;
  const int i = blockIdx.x*512 + t;
  int v = deg[i];
  s[t] = v;
  __syncthreads();
  for (int off=1; off<512; off<<=1){
    int a = (t>=off) ? s[t-off] : 0;
    __syncthreads();
    s[t] += a;
    __syncthreads();
  }
  rowst[i] = s[t] - v;
  if (t==511) bsum[blockIdx.x] = s[511];
}

__global__ void k_scan2(const int* __restrict__ bsum, int* __restrict__ bofs){
  __shared__ int s[256];
  const int t = threadIdx.x;
  int v = bsum[t];
  s[t] = v;
  __syncthreads();
  for (int off=1; off<256; off<<=1){
    int a = (t>=off) ? s[t-off] : 0;
    __syncthreads();
    s[t] += a;
    __syncthreads();
  }
  bofs[t] = s[t] - v;
}

__global__ void k_scan3(int* __restrict__ rowst, const int* __restrict__ bofs){
  int i = blockIdx.x*256 + threadIdx.x;
  rowst[i] += bofs[i>>9];
}

__global__ void k_fill(const int* __restrict__ src, const int* __restrict__ dst,
                       const int* __restrict__ rowst, int* __restrict__ cursor,
                       int* __restrict__ csr){
  int e = blockIdx.x*256 + threadIdx.x;
  int d = dst[e];
  int p = atomicAdd(&cursor[d], 1);
  csr[rowst[d] + p] = src[e];
}

// ---------------- weight prep: B-fragment-swizzled bf16 lin_w (round-4 validated) ----------------
__global__ void k_prepw(const float* __restrict__ lin_w, u16* __restrict__ wsw){
  int tid = blockIdx.x*256 + threadIdx.x;   // 2048 total
  int g = tid >> 6, L = tid & 63;
  int ct = g >> 2, ks = g & 3;
  int o = L & 15, q = L >> 4;
  const float* srcp = lin_w + (ct*16+o)*CN + ks*32 + q*8;
  u16 tmp[8];
  #pragma unroll
  for (int j=0;j<8;++j) tmp[j] = f2bf(srcp[j]);
  *(uint4*)(wsw + (size_t)tid*8) = *(const uint4*)tmp;
}

// ---------------- prep: h fp32 -> h16 natural bf16 + ht16[b][c][n] bf16 ----------------
// grid 64*32, 256 thr; tile = 64 n-rows x 128 c
__global__ void k_prep_h(const float* __restrict__ h, u16* __restrict__ h16, u16* __restrict__ ht16){
  __shared__ u16 st[CN*72];   // st[c*72 + r], r<64
  const int t = threadIdx.x;
  const int b = blockIdx.x >> 5;
  const int n0 = (blockIdx.x & 31)*64;
  const float* srcb = h + ((size_t)b*NPGN + n0)*CN;
  u16* natb = h16 + ((size_t)b*NPGN + n0)*CN;
  #pragma unroll
  for (int j=0;j<8;++j){
    int fidx = (j*256+t)*4;
    int r = fidx>>7, c = fidx&127;
    float4 v = *(const float4*)(srcb + fidx);
    u16 q0=f2bf(v.x), q1=f2bf(v.y), q2=f2bf(v.z), q3=f2bf(v.w);
    ushort4 nv; nv.x=q0; nv.y=q1; nv.z=q2; nv.w=q3;
    *(ushort4*)(natb + fidx) = nv;
    st[(c+0)*72 + r] = q0; st[(c+1)*72 + r] = q1;
    st[(c+2)*72 + r] = q2; st[(c+3)*72 + r] = q3;
  }
  __syncthreads();
  #pragma unroll
  for (int j=0;j<4;++j){
    int oidx = (j*256+t)*8;
    int c = oidx>>6, nn = oidx&63;
    uint4 v = *(const uint4*)&st[c*72 + nn];
    *(uint4*)(ht16 + ((size_t)b*CN + c)*NPGN + n0 + nn) = v;
  }
}

// ---------------- prep: U fp32 -> U16 natural bf16 + Ut16[b][m][n] bf16 ----------------
// grid 64*16, 256 thr; tile = 128 n-rows x 64 m
__global__ void k_prep_U(const float* __restrict__ U, u16* __restrict__ U16, u16* __restrict__ Ut16){
  __shared__ u16 st2[MN*136];   // st2[m*136 + r], r<128
  const int t = threadIdx.x;
  const int b = blockIdx.x >> 4;
  const int n0 = (blockIdx.x & 15)*128;
  const float* srcb = U + ((size_t)b*NPGN + n0)*MN;
  u16* natb = U16 + ((size_t)b*NPGN + n0)*MN;
  #pragma unroll
  for (int j=0;j<8;++j){
    int fidx = (j*256+t)*4;
    int r = fidx>>6, mm = fidx&63;
    float4 v = *(const float4*)(srcb + fidx);
    u16 q0=f2bf(v.x), q1=f2bf(v.y), q2=f2bf(v.z), q3=f2bf(v.w);
    ushort4 nv; nv.x=q0; nv.y=q1; nv.z=q2; nv.w=q3;
    *(ushort4*)(natb + fidx) = nv;
    st2[(mm+0)*136 + r] = q0; st2[(mm+1)*136 + r] = q1;
    st2[(mm+2)*136 + r] = q2; st2[(mm+3)*136 + r] = q3;
  }
  __syncthreads();
  #pragma unroll
  for (int j=0;j<4;++j){
    int oidx = (j*256+t)*8;
    int mm = oidx>>7, nn = oidx&127;
    uint4 v = *(const uint4*)&st2[mm*136 + nn];
    *(uint4*)(Ut16 + ((size_t)b*MN + mm)*NPGN + n0 + nn) = v;
  }
}

// ---------------- h_hat partials (MFMA): hp[q][b][m][c], K-chunk 256 ----------------
// C[m][c] = sum_n Ut16[b][m][n] * ht16[b][c][n]; grid 64*8, 4 waves, wave = m-tile
__global__ __launch_bounds__(256) void k_hhat(const u16* __restrict__ Ut16,
                                              const u16* __restrict__ ht16,
                                              float* __restrict__ hp){
  const int t = threadIdx.x;
  const int L = t & 63, w = t >> 6;
  const int b = blockIdx.x >> 3, q = blockIdx.x & 7;
  const int lo = L & 15, qd = (L >> 4) << 3;
  f32x4 acc[8] = {};
  const u16* Arow  = Ut16 + ((size_t)(b*MN + w*16 + lo))*NPGN + q*256 + qd;
  const u16* Bbase = ht16 + ((size_t)(b*CN + lo))*NPGN + q*256 + qd;
  #pragma unroll
  for (int ks=0; ks<8; ++ks){
    short8 af = *(const short8*)(Arow + ks*32);
    #pragma unroll
    for (int ct=0; ct<8; ++ct){
      short8 bf = *(const short8*)(Bbase + (size_t)ct*16*NPGN + ks*32);
      acc[ct] = __builtin_amdgcn_mfma_f32_16x16x32_bf16(af, bf, acc[ct], 0, 0, 0);
    }
  }
  const int rb = w*16 + ((L>>4)<<2);
  float* dstb = hp + ((size_t)q*BN + b)*MN*CN;
  #pragma unroll
  for (int ct=0; ct<8; ++ct)
    #pragma unroll
    for (int r=0; r<4; ++r)
      dstb[(size_t)(rb+r)*CN + ct*16 + lo] = acc[ct][r];
}

// ---------------- out_hat: sum partials, matvec with W, write ohatT16[b][o][m] ----------------
__global__ void k_ohat(const float* __restrict__ W, const float* __restrict__ hp,
                       u16* __restrict__ ohatT){
  __shared__ u16  sw[CN*CN];    // 32 KB
  __shared__ float shh[CN];
  const int t = threadIdx.x;
  const int m  = blockIdx.x & 63;
  const int bg = blockIdx.x >> 6;
  const float* Wm = W + (size_t)m*CN*CN;
  for (int j=0;j<32;++j){
    int idx = (j*128 + t)*4;
    float4 wv = *(const float4*)(Wm + idx);
    sw[idx+0]=f2bf(wv.x); sw[idx+1]=f2bf(wv.y); sw[idx+2]=f2bf(wv.z); sw[idx+3]=f2bf(wv.w);
  }
  __syncthreads();
  const size_t S = (size_t)BN*MN*CN;
  for (int bb=0; bb<16; ++bb){
    int b = bg*16 + bb;
    size_t base = ((size_t)b*MN + m)*CN + t;
    float a = 0.f;
    #pragma unroll
    for (int p=0;p<8;++p) a += hp[(size_t)p*S + base];
    shh[t] = a;
    __syncthreads();
    float acc = 0.f;
    for (int c=0;c<CN;++c) acc = fmaf(shh[c], bf2f(sw[c*CN+t]), acc);
    ohatT[((size_t)b*CN + t)*MN + m] = f2bf(acc);
    __syncthreads();
  }
}

// ---------------- spec (MFMA): spec16[b,n,o] = sum_m U16[b,n,m]*ohatT[b,o,m] ----------------
// grid 64*16, 4 waves; wave w: n-rows w*32..w*32+31 (2 n-tiles), 8 o-tiles, K=64
__global__ __launch_bounds__(256) void k_spec(const u16* __restrict__ U16,
                                              const u16* __restrict__ ohatT,
                                              u16* __restrict__ spec16){
  const int t = threadIdx.x;
  const int L = t & 63, w = t >> 6;
  const int b = blockIdx.x >> 4;
  const int n0 = (blockIdx.x & 15)*128;
  const int lo = L & 15, qd = (L >> 4) << 3;
  f32x4 acc[2][8] = {};
  const u16* Abase = U16  + ((size_t)(b*NPGN + n0 + w*32 + lo))*MN + qd;
  const u16* Bbase = ohatT + ((size_t)(b*CN + lo))*MN + qd;
  #pragma unroll
  for (int ks=0; ks<2; ++ks){
    short8 a0 = *(const short8*)(Abase + ks*32);
    short8 a1 = *(const short8*)(Abase + (size_t)16*MN + ks*32);
    #pragma unroll
    for (int ot=0; ot<8; ++ot){
      short8 bf = *(const short8*)(Bbase + (size_t)ot*16*MN + ks*32);
      acc[0][ot] = __builtin_amdgcn_mfma_f32_16x16x32_bf16(a0, bf, acc[0][ot], 0, 0, 0);
      acc[1][ot] = __builtin_amdgcn_mfma_f32_16x16x32_bf16(a1, bf, acc[1][ot], 0, 0, 0);
    }
  }
  const int rb = (L>>4)<<2;
  #pragma unroll
  for (int i=0;i<2;++i){
    u16* dstb = spec16 + ((size_t)(b*NPGN + n0 + w*32 + i*16 + rb))*CN + lo;
    #pragma unroll
    for (int ot=0; ot<8; ++ot)
      #pragma unroll
      for (int r=0; r<4; ++r)
        dstb[(size_t)r*CN + ot*16] = f2bf(acc[i][ot][r]);
  }
}

// ---------------- fused: gather-mean + local MFMA + LN + GELU ----------------
__global__ __launch_bounds__(256,4) void k_localep(
    const u16* __restrict__ h16, const u16* __restrict__ spec16,
    const u16* __restrict__ wsw,
    const int* __restrict__ rowst, const int* __restrict__ deg, const int* __restrict__ csr,
    const float* __restrict__ lin_b, const float* __restrict__ ln_g,
    const float* __restrict__ ln_beta, float* __restrict__ out){
  __shared__ u16   sv[32*136];    // 8.7 KB  mean-neighbor rows (bf16, pitch 136)
  __shared__ float sx[32*132];    // 16.9 KB local result
  const int t = threadIdx.x;
  const int w = t>>6, lane = t&63;
  const size_t n0 = (size_t)blockIdx.x*32;

  // Phase A: gather — one wave per node, lane holds channels {2*lane, 2*lane+1}
  for (int it=0; it<8; ++it){
    const int i = it*4 + w;
    const int node = (int)n0 + i;
    const int rs = rowst[node], dg = deg[node];
    float a0=0.f, a1=0.f, b0=0.f, b1=0.f;
    int e = rs, re = rs + dg;
    for (; e+2<=re; e+=2){
      int s0 = csr[e], s1 = csr[e+1];
      u32 p0 = *(const u32*)(h16 + (size_t)s0*CN + lane*2);
      u32 p1 = *(const u32*)(h16 + (size_t)s1*CN + lane*2);
      a0 += bf2f((u16)(p0&0xffffu)); a1 += bf2f((u16)(p0>>16));
      b0 += bf2f((u16)(p1&0xffffu)); b1 += bf2f((u16)(p1>>16));
    }
    if (e<re){
      u32 p0 = *(const u32*)(h16 + (size_t)csr[e]*CN + lane*2);
      a0 += bf2f((u16)(p0&0xffffu)); a1 += bf2f((u16)(p0>>16));
    }
    float inv = 1.0f / fmaxf((float)dg, 1.0f);
    u32 pk = (u32)f2bf((a0+b0)*inv) | ((u32)f2bf((a1+b1)*inv) << 16);
    *(u32*)&sv[i*136 + lane*2] = pk;
  }
  __syncthreads();

  // Phase B: local = sv(32x128) @ lin_w^T via MFMA (round-4 validated layouts)
  const int rt = w&1, cb = w>>1;
  f32x4 acc[4] = {};
  #pragma unroll
  for (int ks=0; ks<4; ++ks){
    short8 af = *(const short8*)&sv[(rt*16 + (lane&15))*136 + ks*32 + ((lane>>4)<<3)];
    #pragma unroll
    for (int c4=0; c4<4; ++c4){
      const short8 bf = *(const short8*)(wsw + ((size_t)((cb*4+c4)*4+ks)*64 + lane)*8);
      acc[c4] = __builtin_amdgcn_mfma_f32_16x16x32_bf16(af, bf, acc[c4], 0, 0, 0);
    }
  }
  #pragma unroll
  for (int c4=0; c4<4; ++c4){
    int col = cb*64 + c4*16 + (lane&15);
    int rb = rt*16 + ((lane>>4)<<2);
    #pragma unroll
    for (int r=0; r<4; ++r) sx[(rb+r)*132 + col] = acc[c4][r];
  }
  __syncthreads();

  // Phase C: x = h + spec + local + bias; LayerNorm; exact GELU
  float2 lb    = *(const float2*)(lin_b  + 2*lane);
  float2 lg    = *(const float2*)(ln_g   + 2*lane);
  float2 lbe   = *(const float2*)(ln_beta+ 2*lane);
  for (int r=0; r<8; ++r){
    int i = r*4 + w;
    size_t base = (n0 + i)*CN + 2*lane;
    u32 hA = *(const u32*)(h16 + base);
    u32 sA = *(const u32*)(spec16 + base);
    float2 loc = *(const float2*)&sx[i*132 + 2*lane];
    float x0 = bf2f((u16)(hA&0xffffu)) + bf2f((u16)(sA&0xffffu)) + loc.x + lb.x;
    float x1 = bf2f((u16)(hA>>16))     + bf2f((u16)(sA>>16))     + loc.y + lb.y;
    float s  = x0 + x1;
    float ss = fmaf(x0,x0, x1*x1);
    #pragma unroll
    for (int d=1; d<64; d<<=1){ s += __shfl_xor(s,d); ss += __shfl_xor(ss,d); }
    float mu  = s*(1.0f/128.0f);
    float var = ss*(1.0f/128.0f) - mu*mu;
    float rstd = rsqrtf(var + 1e-5f);
    float xn0 = (x0-mu)*rstd*lg.x + lbe.x;
    float xn1 = (x1-mu)*rstd*lg.y + lbe.y;
    float2 st;
    st.x = 0.5f*xn0*(1.0f + erff(xn0*0.70710678118654752f));
    st.y = 0.5f*xn1*(1.0f + erff(xn1*0.70710678118654752f));
    *(float2*)(out + base) = st;
  }
}

extern "C" void kernel_launch(void* const* d_in, const int* in_sizes, int n_in,
                              void* d_out, int out_size, void* d_ws, size_t ws_size,
                              hipStream_t stream) {
  const float* h      = (const float*)d_in[0];
  const float* U      = (const float*)d_in[1];
  const float* W      = (const float*)d_in[2];
  const float* lin_w  = (const float*)d_in[3];
  const float* lin_b  = (const float*)d_in[4];
  const float* ln_g   = (const float*)d_in[5];
  const float* ln_b2  = (const float*)d_in[6];
  const int* ei       = (const int*)d_in[7];
  const int* src = ei;
  const int* dst = ei + EN;
  float* out = (float*)d_out;

  char* wp = (char*)d_ws;
  float* hp     = (float*)wp; wp += (size_t)8*BN*MN*CN*sizeof(float);    // 16.8 MB
  u16*   ohatT  = (u16*)wp;   wp += (size_t)BN*CN*MN*sizeof(u16);        // 1.05 MB
  u16*   h16    = (u16*)wp;   wp += (size_t)NN*CN*sizeof(u16);           // 33.5 MB
  u16*   ht16   = (u16*)wp;   wp += (size_t)BN*CN*NPGN*sizeof(u16);      // 33.5 MB
  u16*   U16b   = (u16*)wp;   wp += (size_t)BN*NPGN*MN*sizeof(u16);      // 16.8 MB
  u16*   Ut16   = (u16*)wp;   wp += (size_t)BN*MN*NPGN*sizeof(u16);      // 16.8 MB
  u16*   spec16 = (u16*)wp;   wp += (size_t)NN*CN*sizeof(u16);           // 33.5 MB
  u16*   wsw    = (u16*)wp;   wp += (size_t)CN*CN*sizeof(u16);           // 32 KB
  int*   deg    = (int*)wp;   wp += (size_t)NN*sizeof(int);
  int*   rowst  = (int*)wp;   wp += (size_t)NN*sizeof(int);
  int*   cursor = (int*)wp;   wp += (size_t)NN*sizeof(int);
  int*   csr    = (int*)wp;   wp += (size_t)EN*sizeof(int);              // 4.2 MB
  int*   bsum   = (int*)wp;   wp += 512*sizeof(int);
  int*   bofs   = (int*)wp;   wp += 512*sizeof(int);

  hipMemsetAsync(deg,    0, (size_t)NN*sizeof(int), stream);
  hipMemsetAsync(cursor, 0, (size_t)NN*sizeof(int), stream);

  k_count<<<EN/256, 256, 0, stream>>>(dst, deg);
  k_scan1<<<NN/512, 512, 0, stream>>>(deg, rowst, bsum);
  k_scan2<<<1, 256, 0, stream>>>(bsum, bofs);
  k_scan3<<<NN/256, 256, 0, stream>>>(rowst, bofs);
  k_fill<<<EN/256, 256, 0, stream>>>(src, dst, rowst, cursor, csr);

  k_prepw<<<8, 256, 0, stream>>>(lin_w, wsw);
  k_prep_h<<<BN*32, 256, 0, stream>>>(h, h16, ht16);
  k_prep_U<<<BN*16, 256, 0, stream>>>(U, U16b, Ut16);

  k_hhat<<<BN*8, 256, 0, stream>>>(Ut16, ht16, hp);
  k_ohat<<<256, 128, 0, stream>>>(W, hp, ohatT);
  k_spec<<<BN*16, 256, 0, stream>>>(U16b, ohatT, spec16);

  k_localep<<<NN/32, 256, 0, stream>>>(h16, spec16, wsw, rowst, deg, csr,
                                       lin_b, ln_g, ln_b2, out);
}